// Round 2
// baseline (373.167 us; speedup 1.0000x reference)
//
#include <hip/hip_runtime.h>
#include <math.h>

#define CONF 0.25f
#define NCLS 80
#define RPB  64   // rows per block (256 threads, 4 lanes/row)

// ---------------------------------------------------------------------------
// Pass 1: per-row max + box-sum, block-local reduction.
// 4 lanes per row; lanes 0..3 read the row's 80 floats as 20 float4
// (5 each, interleaved) -> 320B contiguous per row, 20KB contiguous per block.
// Each block emits: block_sum (sum of per-row contribs), block_minfail
// (min row in block with max<CONF, else UINT_MAX), and per-row contrib
// (needed only to resolve the boundary block in pass 2).
// ---------------------------------------------------------------------------
__global__ __launch_bounds__(256) void score_kernel(
    const float* __restrict__ logits,
    const float* __restrict__ boxes,
    float* __restrict__ contrib,               // [k]
    float* __restrict__ block_sum,             // [nb]
    unsigned int* __restrict__ block_minfail,  // [nb]
    unsigned int k)
{
    const int tid   = threadIdx.x;
    const int lane4 = tid & 3;
    const int grp   = tid >> 2;                // row within block, 0..63
    const unsigned int row = blockIdx.x * RPB + (unsigned int)grp;

    __shared__ float        wsum[4];
    __shared__ unsigned int minfail;
    if (tid == 0) minfail = 0xFFFFFFFFu;
    __syncthreads();

    float c = 0.0f;                            // per-row contribution (lane0 of group)
    if (row < k) {
        const float4* rp = (const float4*)(logits + (size_t)row * NCLS);
        float m = -INFINITY;
#pragma unroll
        for (int t = 0; t < 5; ++t) {
            float4 v = rp[lane4 + 4 * t];
            m = fmaxf(m, fmaxf(fmaxf(v.x, v.y), fmaxf(v.z, v.w)));
        }
        m = fmaxf(m, __shfl_xor(m, 1));
        m = fmaxf(m, __shfl_xor(m, 2));
        if (lane4 == 0) {
            float4 b = ((const float4*)boxes)[row];
            c = m + ((b.x + b.y) + (b.z + b.w));
            contrib[row] = c;
            if (m < CONF) atomicMin(&minfail, row);   // statistically never
        }
    }

    // Sum c across the wave: nonzero values sit at lanes = 0 mod 4.
    c += __shfl_down(c, 32);
    c += __shfl_down(c, 16);
    c += __shfl_down(c, 8);
    c += __shfl_down(c, 4);
    const int lane = tid & 63, wid = tid >> 6;
    if (lane == 0) wsum[wid] = c;
    __syncthreads();
    if (tid == 0) {
        block_sum[blockIdx.x]     = (wsum[0] + wsum[1]) + (wsum[2] + wsum[3]);
        block_minfail[blockIdx.x] = minfail;
    }
}

// ---------------------------------------------------------------------------
// Pass 2 (one block): global first-fail j, then total =
//   sum(block_sum[0 .. j/64)) + sum(contrib[j/64*64 .. j)).
// Reads ~32KB (L2-hot). Deterministic.
// ---------------------------------------------------------------------------
__global__ __launch_bounds__(256) void combine_kernel(
    const float* __restrict__ contrib,
    const float* __restrict__ block_sum,
    const unsigned int* __restrict__ block_minfail,
    float* __restrict__ out,
    unsigned int k, unsigned int nb)
{
    const int tid  = threadIdx.x;
    const int lane = tid & 63, wid = tid >> 6;

    // global min over block_minfail
    unsigned int mf = 0xFFFFFFFFu;
    for (unsigned int b = tid; b < nb; b += 256)
        mf = min(mf, block_minfail[b]);
#pragma unroll
    for (int o = 32; o > 0; o >>= 1) mf = min(mf, __shfl_down(mf, o));
    __shared__ unsigned int mfs[4];
    if (lane == 0) mfs[wid] = mf;
    __syncthreads();
    unsigned int j = min(min(mfs[0], mfs[1]), min(mfs[2], mfs[3]));
    if (j > k) j = k;

    const unsigned int fullb = j / RPB;
    float s = 0.0f;
    for (unsigned int b = tid; b < fullb; b += 256)
        s += block_sum[b];
    for (unsigned int i = fullb * RPB + tid; i < j; i += 256)
        s += contrib[i];

#pragma unroll
    for (int o = 32; o > 0; o >>= 1) s += __shfl_down(s, o);
    __shared__ float ss[4];
    if (lane == 0) ss[wid] = s;
    __syncthreads();
    if (tid == 0) out[0] = (ss[0] + ss[1]) + (ss[2] + ss[3]);
}

extern "C" void kernel_launch(void* const* d_in, const int* in_sizes, int n_in,
                              void* d_out, int out_size, void* d_ws, size_t ws_size,
                              hipStream_t stream) {
    const float* logits = (const float*)d_in[0];
    const float* boxes  = (const float*)d_in[1];
    float* out = (float*)d_out;

    const unsigned int N = (unsigned int)(in_sizes[0] / NCLS);
    unsigned int k = N / 4;                  // RATIO = 0.25, int truncation
    if (k < 1) k = 1;
    const unsigned int nb = (k + RPB - 1) / RPB;

    // ws layout: contrib [k f32] | block_sum [nb f32] | block_minfail [nb u32]
    char* ws = (char*)d_ws;
    size_t off_bs = (((size_t)k * 4) + 255) & ~(size_t)255;
    size_t off_mf = (off_bs + (size_t)nb * 4 + 255) & ~(size_t)255;
    float*        contrib       = (float*)ws;
    float*        block_sum     = (float*)(ws + off_bs);
    unsigned int* block_minfail = (unsigned int*)(ws + off_mf);

    score_kernel<<<nb, 256, 0, stream>>>(logits, boxes, contrib, block_sum,
                                         block_minfail, k);
    combine_kernel<<<1, 256, 0, stream>>>(contrib, block_sum, block_minfail,
                                          out, k, nb);
}